// Round 1
// baseline (224.328 us; speedup 1.0000x reference)
//
#include <hip/hip_runtime.h>

#define C_    19
#define NB    15
#define CB    (C_ * NB)          // 285 (class,bin) cells
#define HW    (512 * 1024)       // 524288
#define NPIX  (4 * HW)           // 2097152
#define REPS  32                 // LDS histogram replicas (one per bank-ish)
#define TPB   256
#define GBLK  1024
#define KCOP  8                  // global histogram copies (contention spread)

// Kernel 1: softmax over C per pixel, histogram conf_sum and acc_sum per (class,bin).
// Uses |conf_sum - acc_sum| identity downstream, so no counts needed.
__global__ __launch_bounds__(TPB, 4)
void ece_hist(const float* __restrict__ logits,
              const int*   __restrict__ labels,
              float*       __restrict__ ws) {
    __shared__ float hconf[REPS * CB];   // replicated conf_sum hist (36480 B)
    __shared__ float hacc[CB];           // acc_sum hist (1 atomic/pixel, low contention)

    const int tid = threadIdx.x;
    for (int i = tid; i < REPS * CB; i += TPB) hconf[i] = 0.f;
    for (int i = tid; i < CB; i += TPB) hacc[i] = 0.f;
    __syncthreads();

    float* myh = hconf + (tid & (REPS - 1)) * CB;  // stride 285: replicas land on distinct banks

    const int nGroups = NPIX / 2;                  // 2 pixels per thread-group (float2 loads)
    for (int g = blockIdx.x * TPB + tid; g < nGroups; g += gridDim.x * TPB) {
        const int n  = g << 1;
        const int b  = n >> 19;                    // HW = 2^19
        const int hw = n & (HW - 1);
        const float* base = logits + ((size_t)b * C_) * HW + hw;

        float2 v[C_];
#pragma unroll
        for (int c = 0; c < C_; ++c)
            v[c] = *reinterpret_cast<const float2*>(base + (size_t)c * HW);
        const int2 lab = *reinterpret_cast<const int2*>(labels + n);

#pragma unroll
        for (int p = 0; p < 2; ++p) {
            float x[C_];
#pragma unroll
            for (int c = 0; c < C_; ++c) x[c] = p ? v[c].y : v[c].x;
            const int l = p ? lab.y : lab.x;

            float m = x[0];
#pragma unroll
            for (int c = 1; c < C_; ++c) m = fmaxf(m, x[c]);
            float s = 0.f;
#pragma unroll
            for (int c = 0; c < C_; ++c) { float e = __expf(x[c] - m); x[c] = e; s += e; }
            const float inv = 1.f / s;

            float confl = 0.f;
#pragma unroll
            for (int c = 0; c < C_; ++c) {
                const float conf = x[c] * inv;
                int bin = (int)ceilf(conf * (float)NB) - 1;
                bin = bin < 0 ? 0 : (bin > NB - 1 ? NB - 1 : bin);
                atomicAdd(&myh[c * NB + bin], conf);   // conf==0 adds nothing -> matches 'valid' mask
                if (c == l) confl = conf;              // cndmask gather, no runtime indexing
            }
            if (confl > 0.f) {                         // 'valid' guard for accuracy count
                int binl = (int)ceilf(confl * (float)NB) - 1;
                binl = binl < 0 ? 0 : (binl > NB - 1 ? NB - 1 : binl);
                atomicAdd(&hacc[l * NB + binl], 1.f);
            }
        }
    }
    __syncthreads();

    // Flush block histogram into one of KCOP global copies.
    float* wsbase = ws + (size_t)(blockIdx.x & (KCOP - 1)) * (2 * CB);
    for (int i = tid; i < CB; i += TPB) {
        float s = 0.f;
#pragma unroll
        for (int r = 0; r < REPS; ++r) s += hconf[r * CB + i];
        atomicAdd(&wsbase[i], s);
        atomicAdd(&wsbase[CB + i], hacc[i]);
    }
}

// Kernel 2: fold KCOP copies, sce = mean_c sum_b |conf_sum - acc_sum| / N
__global__ void ece_final(const float* __restrict__ ws, float* __restrict__ out) {
    const int t = threadIdx.x;  // 320 threads = 5 waves
    float val = 0.f;
    if (t < CB) {
        float s = 0.f, a = 0.f;
#pragma unroll
        for (int k = 0; k < KCOP; ++k) {
            s += ws[k * (2 * CB) + t];
            a += ws[k * (2 * CB) + CB + t];
        }
        val = fabsf(s - a);
    }
#pragma unroll
    for (int off = 32; off; off >>= 1) val += __shfl_down(val, off);
    __shared__ float sm[5];
    if ((t & 63) == 0) sm[t >> 6] = val;
    __syncthreads();
    if (t == 0) {
        float tot = sm[0] + sm[1] + sm[2] + sm[3] + sm[4];
        out[0] = tot / ((float)NPIX * (float)C_);
    }
}

extern "C" void kernel_launch(void* const* d_in, const int* in_sizes, int n_in,
                              void* d_out, int out_size, void* d_ws, size_t ws_size,
                              hipStream_t stream) {
    const float* logits = (const float*)d_in[0];
    const int*   labels = (const int*)d_in[1];
    float* out = (float*)d_out;
    float* ws  = (float*)d_ws;

    hipMemsetAsync(ws, 0, (size_t)KCOP * 2 * CB * sizeof(float), stream);
    ece_hist<<<GBLK, TPB, 0, stream>>>(logits, labels, ws);
    ece_final<<<1, 320, 0, stream>>>(ws, out);
}

// Round 2
// 58.985 us; speedup vs baseline: 3.8031x; 3.8031x over previous
//
#include <hip/hip_runtime.h>

#define C_    19
#define NB    15
#define CB    (C_ * NB)          // 285 cells
#define HW    (512 * 1024)
#define NPIX  (4 * HW)           // 2097152
#define REPS  8                  // LDS histogram replicas
#define TPB   256
#define GBLK  1024
#define KCOP  8                  // global histogram copies

// Softmax per pixel; bins 0-1 conf sums + bin-0 acc counts in registers
// (covers ~92% of contributions for this data); LDS atomics only for the
// rare bin>=2 conf and bin>=1 acc. |conf_sum - acc_sum| identity downstream.
__global__ __launch_bounds__(TPB, 4)
void ece_hist(const float* __restrict__ logits,
              const int*   __restrict__ labels,
              float*       __restrict__ ws) {
    __shared__ float hconf[REPS * CB];   // 9120 B
    __shared__ float hacc[REPS * CB];    // 9120 B

    const int tid = threadIdx.x;
    for (int i = tid; i < REPS * CB; i += TPB) { hconf[i] = 0.f; hacc[i] = 0.f; }
    __syncthreads();

    const int rep = tid & (REPS - 1);
    float* myconf = hconf + rep * CB;
    float* myacc  = hacc  + rep * CB;

    float c0[C_], c1[C_], a0[C_];        // register accumulators: bin0/bin1 conf, bin0 acc
#pragma unroll
    for (int c = 0; c < C_; ++c) { c0[c] = 0.f; c1[c] = 0.f; a0[c] = 0.f; }

    for (int n = blockIdx.x * TPB + tid; n < NPIX; n += GBLK * TPB) {
        const int b  = n >> 19;                    // HW = 2^19
        const int hw = n & (HW - 1);
        const float* base = logits + ((size_t)b * C_) * HW + hw;

        float x[C_];
#pragma unroll
        for (int c = 0; c < C_; ++c) x[c] = base[(size_t)c * HW];
        const int l = labels[n];

        float m = x[0];
#pragma unroll
        for (int c = 1; c < C_; ++c) m = fmaxf(m, x[c]);
        float s = 0.f;
#pragma unroll
        for (int c = 0; c < C_; ++c) { float e = __expf(x[c] - m); x[c] = e; s += e; }
        const float inv = 1.f / s;

        int lbin = 0;
#pragma unroll
        for (int c = 0; c < C_; ++c) {
            const float conf = x[c] * inv;
            int bin = (int)ceilf(conf * (float)NB) - 1;      // same binning as reference
            bin = bin < 0 ? 0 : (bin > NB - 1 ? NB - 1 : bin);
            c0[c] += (bin == 0) ? conf : 0.f;                // conf==0 adds 0 -> matches valid mask
            c1[c] += (bin == 1) ? conf : 0.f;
            const bool isl = (c == l);
            a0[c] += (isl && bin == 0 && conf > 0.f) ? 1.f : 0.f;
            if (bin >= 2) atomicAdd(&myconf[c * NB + bin], conf);
            if (isl) lbin = bin;
        }
        if (lbin >= 1) atomicAdd(&myacc[l * NB + lbin], 1.f);  // bin>=1 implies conf>0
    }

    // Flush register accumulators: 3-step xor-shuffle (8-lane groups), then
    // one LDS atomic per group into replica (tid>>3)&7 -> 8 distinct banks.
#pragma unroll
    for (int c = 0; c < C_; ++c) {
        float v0 = c0[c], v1 = c1[c], va = a0[c];
        v0 += __shfl_xor(v0, 1); v1 += __shfl_xor(v1, 1); va += __shfl_xor(va, 1);
        v0 += __shfl_xor(v0, 2); v1 += __shfl_xor(v1, 2); va += __shfl_xor(va, 2);
        v0 += __shfl_xor(v0, 4); v1 += __shfl_xor(v1, 4); va += __shfl_xor(va, 4);
        if ((tid & 7) == 0) {
            const int r = (tid >> 3) & (REPS - 1);
            atomicAdd(&hconf[r * CB + c * NB + 0], v0);
            atomicAdd(&hconf[r * CB + c * NB + 1], v1);
            atomicAdd(&hacc [r * CB + c * NB + 0], va);
        }
    }
    __syncthreads();

    // Block flush into one of KCOP global copies.
    float* wsbase = ws + (size_t)(blockIdx.x & (KCOP - 1)) * (2 * CB);
    for (int i = tid; i < CB; i += TPB) {
        float sc = 0.f, sa = 0.f;
#pragma unroll
        for (int r = 0; r < REPS; ++r) { sc += hconf[r * CB + i]; sa += hacc[r * CB + i]; }
        atomicAdd(&wsbase[i], sc);
        atomicAdd(&wsbase[CB + i], sa);
    }
}

// Fold KCOP copies: sce = mean_c sum_b |conf_sum - acc_sum| / N
__global__ void ece_final(const float* __restrict__ ws, float* __restrict__ out) {
    const int t = threadIdx.x;  // 320 threads = 5 waves
    float val = 0.f;
    if (t < CB) {
        float s = 0.f, a = 0.f;
#pragma unroll
        for (int k = 0; k < KCOP; ++k) {
            s += ws[k * (2 * CB) + t];
            a += ws[k * (2 * CB) + CB + t];
        }
        val = fabsf(s - a);
    }
#pragma unroll
    for (int off = 32; off; off >>= 1) val += __shfl_down(val, off);
    __shared__ float sm[5];
    if ((t & 63) == 0) sm[t >> 6] = val;
    __syncthreads();
    if (t == 0) {
        float tot = sm[0] + sm[1] + sm[2] + sm[3] + sm[4];
        out[0] = tot / ((float)NPIX * (float)C_);
    }
}

extern "C" void kernel_launch(void* const* d_in, const int* in_sizes, int n_in,
                              void* d_out, int out_size, void* d_ws, size_t ws_size,
                              hipStream_t stream) {
    const float* logits = (const float*)d_in[0];
    const int*   labels = (const int*)d_in[1];
    float* out = (float*)d_out;
    float* ws  = (float*)d_ws;

    hipMemsetAsync(ws, 0, (size_t)KCOP * 2 * CB * sizeof(float), stream);
    ece_hist<<<GBLK, TPB, 0, stream>>>(logits, labels, ws);
    ece_final<<<1, 320, 0, stream>>>(ws, out);
}